// Round 8
// baseline (558.751 us; speedup 1.0000x reference)
//
#include <hip/hip_runtime.h>
#include <hip/hip_bf16.h>

#define HID 128

typedef __attribute__((ext_vector_type(8))) short short8;
typedef __attribute__((ext_vector_type(4))) float f32x4;

__device__ __forceinline__ unsigned short f2bf(float f) {
    unsigned int u = __builtin_bit_cast(unsigned int, f);
    u += 0x7FFFu + ((u >> 16) & 1u);            // round-to-nearest-even
    return (unsigned short)(u >> 16);
}
__device__ __forceinline__ float bf2f(unsigned short h) {
    unsigned int u = ((unsigned int)h) << 16;
    return __builtin_bit_cast(float, u);
}

// ---------------- prep: x -> bf16 ----------------
__global__ void prep_x(const float4* __restrict__ x4, unsigned short* __restrict__ xb, int n4) {
    int t = blockIdx.x * 256 + threadIdx.x;
    if (t >= n4) return;
    float4 v = x4[t];
    union { unsigned short u[4]; uint2 d; } p;
    p.u[0] = f2bf(v.x); p.u[1] = f2bf(v.y); p.u[2] = f2bf(v.z); p.u[3] = f2bf(v.w);
    *(uint2*)(xb + (size_t)t * 4) = p.d;
}

// ---------------- prep: W[k][128] -> fragment order Wf[ks][nt][lane][j] ----------------
__global__ void prep_w(const float* __restrict__ W, unsigned short* __restrict__ Wf, int nks) {
    int t = blockIdx.x * 256 + threadIdx.x;
    if (t >= nks * 8 * 64) return;
    int lane = t & 63, nt = (t >> 6) & 7, ks = t >> 9;
    int kb  = ks * 32 + ((lane >> 4) << 3);
    int col = (nt << 4) + (lane & 15);
    union { unsigned short u[8]; uint4 q; } p;
    #pragma unroll
    for (int j = 0; j < 8; ++j) p.u[j] = f2bf(W[(size_t)(kb + j) * 128 + col]);
    *(uint4*)(Wf + (size_t)t * 8) = p.q;
}

// hi/lo split version for near-fp32 node GEMMs
__global__ void prep_w_split(const float* __restrict__ W,
                             unsigned short* __restrict__ Wh,
                             unsigned short* __restrict__ Wl, int nks) {
    int t = blockIdx.x * 256 + threadIdx.x;
    if (t >= nks * 8 * 64) return;
    int lane = t & 63, nt = (t >> 6) & 7, ks = t >> 9;
    int kb  = ks * 32 + ((lane >> 4) << 3);
    int col = (nt << 4) + (lane & 15);
    union { unsigned short u[8]; uint4 q; } ph, pl;
    #pragma unroll
    for (int j = 0; j < 8; ++j) {
        float w = W[(size_t)(kb + j) * 128 + col];
        unsigned short h = f2bf(w);
        ph.u[j] = h;
        pl.u[j] = f2bf(w - bf2f(h));
    }
    *(uint4*)(Wh + (size_t)t * 8) = ph.q;
    *(uint4*)(Wl + (size_t)t * 8) = pl.q;
}

// ---------------- counting sort of edges by dst (perm only) ----------------
__global__ void hist_k(const int* __restrict__ ei, unsigned* __restrict__ cnt, int E) {
    int e = blockIdx.x * 256 + threadIdx.x;
    if (e < E) atomicAdd(&cnt[ei[E + e]], 1u);
}

__global__ void scan_k(const unsigned* __restrict__ cnt, unsigned* __restrict__ cur, int n) {
    __shared__ unsigned wsum[16];
    int tid = threadIdx.x, lane = tid & 63, w = tid >> 6;
    unsigned carry = 0;
    for (int base = 0; base < n; base += 1024) {
        int i = base + tid;
        unsigned v = (i < n) ? cnt[i] : 0u;
        unsigned s = v;
        #pragma unroll
        for (int off = 1; off < 64; off <<= 1) {
            unsigned t = __shfl_up(s, off);
            if (lane >= off) s += t;
        }
        if (lane == 63) wsum[w] = s;
        __syncthreads();
        if (tid < 16) {
            unsigned t = wsum[tid];
            #pragma unroll
            for (int off = 1; off < 16; off <<= 1) {
                unsigned u = __shfl_up(t, off);
                if (tid >= off) t += u;
            }
            wsum[tid] = t;
        }
        __syncthreads();
        unsigned woff = (w == 0) ? 0u : wsum[w - 1];
        if (i < n) cur[i] = carry + woff + s - v;
        unsigned tot = wsum[15];
        __syncthreads();
        carry += tot;
    }
}

__global__ void scatter_perm_k(const int* __restrict__ ei, unsigned* __restrict__ cur,
                               int* __restrict__ perm, int E) {
    int e = blockIdx.x * 256 + threadIdx.x;
    if (e >= E) return;
    unsigned pos = atomicAdd(&cur[ei[E + e]], 1u);
    perm[pos] = e;
}

// ---------------- T_dst = x @ W1[128:256]  (dense, per node, f32 out) ----------------
__global__ __launch_bounds__(256, 4)
void dst_gemm(const unsigned short* __restrict__ xb,
              const unsigned short* __restrict__ W1f,
              float* __restrict__ Tdst, int N)
{
    const int lane = threadIdx.x & 63;
    const int wid  = threadIdx.x >> 6;
    const int n0   = (blockIdx.x * 4 + wid) * 16;
    if (n0 >= N) return;
    const int arow = lane & 15;
    const int g4   = lane >> 4;

    int nr = n0 + arow; if (nr >= N) nr = N - 1;
    const unsigned short* px = xb + (size_t)nr * 128 + g4 * 8;

    f32x4 acc[8];
    #pragma unroll
    for (int i = 0; i < 8; ++i) acc[i] = (f32x4)0.f;

    #pragma unroll
    for (int ks = 0; ks < 4; ++ks) {
        short8 a = *(const short8*)(px + ks * 32);
        #pragma unroll
        for (int nt = 0; nt < 8; ++nt) {
            short8 bf = *(const short8*)(W1f + (size_t)(((ks + 4) * 8 + nt) * 64 + lane) * 8);
            acc[nt] = __builtin_amdgcn_mfma_f32_16x16x32_bf16(a, bf, acc[nt], 0, 0, 0);
        }
    }
    #pragma unroll
    for (int nt = 0; nt < 8; ++nt) {
        int col = nt * 16 + arow;
        #pragma unroll
        for (int r = 0; r < 4; ++r) {
            int node = n0 + g4 * 4 + r;
            if (node < N) Tdst[(size_t)node * 128 + col] = acc[nt][r];
        }
    }
}

// ---------------- Edge kernel: M=32/wave, 2 streams share B ----------------
// TD=true: only src rows staged (8 KB/wave); dst term added from Tdst. 4 blocks/CU.
// TD=false: src+dst staged (16 KB/wave, r7 fallback). 2 blocks/CU.
template<bool TD>
__global__ __launch_bounds__(256, TD ? 4 : 2)
void edge_mfma(const unsigned short* __restrict__ xb,   // [N][128] bf16
               const int* __restrict__ ei,              // [2][E]
               const int* __restrict__ perm,            // dst-sorted order, may be null
               const float* __restrict__ ea,            // [E][3]
               const float* __restrict__ Tdst,          // [N][128] f32 (TD only)
               const unsigned short* __restrict__ W1f,  // [8][8][64][8] bf16
               const unsigned short* __restrict__ W2f,  // [4][8][64][8] bf16
               const float* __restrict__ W1tail,        // [3][128] fp32
               const float* __restrict__ bm1,
               const float* __restrict__ bm2,
               float* __restrict__ agg,
               int E)
{
    __shared__ alignas(16) char As[4][TD ? 8192 : 16384];
    __shared__ float sW1e[3 * 128];
    __shared__ float sB1[128], sB2[128];
    __shared__ int   sIdx[4][64];   // [0:32) src node, [32:64) dst node
    __shared__ float sEA[4][96];

    const int tid  = threadIdx.x;
    const int lane = tid & 63;
    const int w    = tid >> 6;
    const int e0w  = blockIdx.x * 128 + w * 32;

    if (tid < 128) {
        sW1e[tid]       = W1tail[tid];
        sW1e[128 + tid] = W1tail[128 + tid];
        sW1e[256 + tid] = W1tail[256 + tid];
        sB1[tid] = bm1[tid];
        sB2[tid] = bm2[tid];
    }
    {
        int sl = lane & 31;
        int e  = e0w + sl; int ec = (e < E) ? e : (E - 1);
        int pe = perm ? perm[ec] : ec;
        sIdx[w][lane] = (lane < 32) ? ei[pe] : ei[E + pe];
    }
    for (int j = lane; j < 96; j += 64) {
        int eidx = e0w + j / 3, c = j - (j / 3) * 3;
        float v = 0.f;
        if (eidx < E) {
            int pe = perm ? perm[eidx] : eidx;
            v = ea[(size_t)pe * 3 + c];
        }
        sEA[w][j] = v;
    }

    char* Aw = As[w];
    const int arow  = lane & 15;
    const int kgrp  = (lane >> 4) << 4;
    const int rbase = (lane >> 4) * 4;

    // ---- gather into swizzled LDS ----
    if constexpr (TD) {
        // 32 src rows x 256 B
        #pragma unroll
        for (int it = 0; it < 8; ++it) {
            int g = it * 64 + lane;
            int r = g >> 4, c = g & 15;
            int node = sIdx[w][r];
            uint4 v = *(const uint4*)(xb + (size_t)node * 128 + c * 8);
            *(uint4*)(Aw + r * 256 + ((c * 16) ^ ((r & 15) << 4))) = v;
        }
    } else {
        // 32 edges x (src 256 B | dst 256 B) = 512 B rows
        #pragma unroll
        for (int it = 0; it < 16; ++it) {
            int g = it * 64 + lane;
            int rr = g >> 4, c = g & 15;
            int el = rr & 31, half = rr >> 5;
            int node = sIdx[w][half * 32 + el];
            uint4 v = *(const uint4*)(xb + (size_t)node * 128 + c * 8);
            *(uint4*)(Aw + el * 512 + ((half * 256 + c * 16) ^ ((el & 15) << 4))) = v;
        }
    }
    __syncthreads();

    constexpr int KS1 = TD ? 4 : 8;
    constexpr int AST = TD ? 256 : 512;

    // ---- GEMM1: two 16-row streams share B-frags ----
    f32x4 acc0[8], acc1[8];
    #pragma unroll
    for (int i = 0; i < 8; ++i) { acc0[i] = (f32x4)0.f; acc1[i] = (f32x4)0.f; }

    #pragma unroll
    for (int ks = 0; ks < KS1; ++ks) {
        int cb = ks * 64 + kgrp;
        short8 a0 = *(const short8*)(Aw + arow * AST        + (cb ^ (arow << 4)));
        short8 a1 = *(const short8*)(Aw + (16 + arow) * AST + (cb ^ (arow << 4)));
        #pragma unroll
        for (int nt = 0; nt < 8; ++nt) {
            short8 bf = *(const short8*)(W1f + (size_t)((ks * 8 + nt) * 64 + lane) * 8);
            acc0[nt] = __builtin_amdgcn_mfma_f32_16x16x32_bf16(a0, bf, acc0[nt], 0, 0, 0);
            acc1[nt] = __builtin_amdgcn_mfma_f32_16x16x32_bf16(a1, bf, acc1[nt], 0, 0, 0);
        }
    }

    // ---- epilogue 1: (+ T_dst) + edge_attr (fp32) + bias, relu, store H bf16 ----
    float a0e[2][4], a1e[2][4], a2e[2][4];
    int   dv[2][4];
    #pragma unroll
    for (int m = 0; m < 2; ++m)
        #pragma unroll
        for (int r = 0; r < 4; ++r) {
            int el = m * 16 + rbase + r;
            a0e[m][r] = sEA[w][el * 3 + 0];
            a1e[m][r] = sEA[w][el * 3 + 1];
            a2e[m][r] = sEA[w][el * 3 + 2];
            dv[m][r]  = sIdx[w][32 + el];
        }
    #pragma unroll
    for (int nt = 0; nt < 8; ++nt) {
        int col = (nt << 4) + arow;
        float w0 = sW1e[col], w1 = sW1e[128 + col], w2 = sW1e[256 + col];
        float bb = sB1[col];
        #pragma unroll
        for (int m = 0; m < 2; ++m) {
            const f32x4& A = m ? acc1[nt] : acc0[nt];
            #pragma unroll
            for (int r = 0; r < 4; ++r) {
                int el = m * 16 + rbase + r;
                float h = A[r] + bb;
                if constexpr (TD) h += Tdst[(size_t)dv[m][r] * 128 + col];
                h = fmaf(a0e[m][r], w0, h);
                h = fmaf(a1e[m][r], w1, h);
                h = fmaf(a2e[m][r], w2, h);
                h = fmaxf(h, 0.f);
                *(unsigned short*)(Aw + el * 256 + ((col * 2) ^ ((el & 15) << 4))) = f2bf(h);
            }
        }
    }
    __syncthreads();

    // ---- GEMM2: H[32,128] @ [128,128] ----
    #pragma unroll
    for (int i = 0; i < 8; ++i) { acc0[i] = (f32x4)0.f; acc1[i] = (f32x4)0.f; }
    #pragma unroll
    for (int ks = 0; ks < 4; ++ks) {
        int cb = ks * 64 + kgrp;
        short8 a0 = *(const short8*)(Aw + arow * 256        + (cb ^ (arow << 4)));
        short8 a1 = *(const short8*)(Aw + (16 + arow) * 256 + (cb ^ (arow << 4)));
        #pragma unroll
        for (int nt = 0; nt < 8; ++nt) {
            short8 bf = *(const short8*)(W2f + (size_t)((ks * 8 + nt) * 64 + lane) * 8);
            acc0[nt] = __builtin_amdgcn_mfma_f32_16x16x32_bf16(a0, bf, acc0[nt], 0, 0, 0);
            acc1[nt] = __builtin_amdgcn_mfma_f32_16x16x32_bf16(a1, bf, acc1[nt], 0, 0, 0);
        }
    }

    // ---- epilogue 2: + bias, run-merged atomic scatter-add into agg[dst] ----
    #pragma unroll
    for (int nt = 0; nt < 8; ++nt) {
        int col = (nt << 4) + arow;
        float bb = sB2[col];
        #pragma unroll
        for (int m = 0; m < 2; ++m) {
            const f32x4& A = m ? acc1[nt] : acc0[nt];
            float carry = 0.f;
            int   cd    = -1;
            #pragma unroll
            for (int r = 0; r < 4; ++r) {
                int eg = e0w + m * 16 + rbase + r;
                if (eg < E) {
                    float v = A[r] + bb;
                    if (dv[m][r] == cd) {
                        carry += v;
                    } else {
                        if (cd >= 0) unsafeAtomicAdd(agg + (size_t)cd * 128 + col, carry);
                        cd = dv[m][r];
                        carry = v;
                    }
                }
            }
            if (cd >= 0) unsafeAtomicAdd(agg + (size_t)cd * 128 + col, carry);
        }
    }
}

// ---------------- Node kernel: bf16 MFMA with hi/lo split (near-fp32) ----------------
__global__ __launch_bounds__(256, 3)
void node_mfma(const float* __restrict__ x,
               const float* __restrict__ agg,
               const unsigned short* __restrict__ WgH, const unsigned short* __restrict__ WgL,
               const unsigned short* __restrict__ Wu1H, const unsigned short* __restrict__ Wu1L,
               const unsigned short* __restrict__ Wu2H, const unsigned short* __restrict__ Wu2L,
               const float* __restrict__ bg, const float* __restrict__ bu1,
               const float* __restrict__ bu2,
               const float* __restrict__ gamma, const float* __restrict__ beta,
               float* __restrict__ out, int N)
{
    __shared__ alignas(16) char Hs[4][8192];

    const int tid  = threadIdx.x;
    const int lane = tid & 63;
    const int wid  = tid >> 6;
    const int n0   = (blockIdx.x * 4 + wid) * 16;
    if (n0 >= N) return;

    const int arow = lane & 15;
    const int g4   = lane >> 4;

    int nr = n0 + arow; if (nr >= N) nr = N - 1;
    const float* px = x   + (size_t)nr * 128 + g4 * 8;
    const float* pa = agg + (size_t)nr * 128 + g4 * 8;

    short8 ah[8], al[8];
    #pragma unroll
    for (int ks = 0; ks < 8; ++ks) {
        const float* p = (ks < 4) ? (px + ks * 32) : (pa + (ks - 4) * 32);
        float4 v0 = *(const float4*)p;
        float4 v1 = *(const float4*)(p + 4);
        float v[8] = { v0.x, v0.y, v0.z, v0.w, v1.x, v1.y, v1.z, v1.w };
        #pragma unroll
        for (int j = 0; j < 8; ++j) {
            unsigned short h = f2bf(v[j]);
            ah[ks][j] = (short)h;
            al[ks][j] = (short)f2bf(v[j] - bf2f(h));
        }
    }

    f32x4 ga[8];
    #pragma unroll
    for (int i = 0; i < 8; ++i) ga[i] = (f32x4)0.f;
    #pragma unroll
    for (int ks = 0; ks < 8; ++ks) {
        #pragma unroll
        for (int nt = 0; nt < 8; ++nt) {
            size_t o = (size_t)((ks * 8 + nt) * 64 + lane) * 8;
            short8 bh = *(const short8*)(WgH + o);
            short8 bl = *(const short8*)(WgL + o);
            ga[nt] = __builtin_amdgcn_mfma_f32_16x16x32_bf16(ah[ks], bh, ga[nt], 0, 0, 0);
            ga[nt] = __builtin_amdgcn_mfma_f32_16x16x32_bf16(al[ks], bh, ga[nt], 0, 0, 0);
            ga[nt] = __builtin_amdgcn_mfma_f32_16x16x32_bf16(ah[ks], bl, ga[nt], 0, 0, 0);
        }
    }

    f32x4 ua[8];
    #pragma unroll
    for (int i = 0; i < 8; ++i) ua[i] = (f32x4)0.f;
    #pragma unroll
    for (int ks = 0; ks < 8; ++ks) {
        #pragma unroll
        for (int nt = 0; nt < 8; ++nt) {
            size_t o = (size_t)((ks * 8 + nt) * 64 + lane) * 8;
            short8 bh = *(const short8*)(Wu1H + o);
            short8 bl = *(const short8*)(Wu1L + o);
            ua[nt] = __builtin_amdgcn_mfma_f32_16x16x32_bf16(ah[ks], bh, ua[nt], 0, 0, 0);
            ua[nt] = __builtin_amdgcn_mfma_f32_16x16x32_bf16(al[ks], bh, ua[nt], 0, 0, 0);
            ua[nt] = __builtin_amdgcn_mfma_f32_16x16x32_bf16(ah[ks], bl, ua[nt], 0, 0, 0);
        }
    }

    #pragma unroll
    for (int nt = 0; nt < 8; ++nt) {
        int col = nt * 16 + arow;
        float b1 = bu1[col];
        #pragma unroll
        for (int r = 0; r < 4; ++r) {
            int row = g4 * 4 + r;
            float u = fmaxf(ua[nt][r] + b1, 0.f);
            unsigned short h = f2bf(u);
            unsigned short l = f2bf(u - bf2f(h));
            unsigned int pk = (unsigned int)h | ((unsigned int)l << 16);
            *(unsigned int*)(&Hs[wid][row * 512 + ((col * 4) ^ ((row & 15) << 4))]) = pk;
        }
    }

    #pragma unroll
    for (int nt = 0; nt < 8; ++nt) {
        int col = nt * 16 + arow;
        float b = bg[col];
        #pragma unroll
        for (int r = 0; r < 4; ++r)
            ga[nt][r] = 1.f / (1.f + expf(-(ga[nt][r] + b)));
    }
    __syncthreads();

    f32x4 u2[8];
    #pragma unroll
    for (int i = 0; i < 8; ++i) u2[i] = (f32x4)0.f;
    #pragma unroll
    for (int ks = 0; ks < 4; ++ks) {
        int b0 = ks * 128 + g4 * 32;
        unsigned int q0[4], q1[4];
        *(uint4*)q0 = *(const uint4*)(&Hs[wid][arow * 512 + ( b0       ^ (arow << 4))]);
        *(uint4*)q1 = *(const uint4*)(&Hs[wid][arow * 512 + ((b0 + 16) ^ (arow << 4))]);
        short8 a2h, a2l;
        #pragma unroll
        for (int j = 0; j < 4; ++j) {
            a2h[j]     = (short)(q0[j] & 0xffff);
            a2l[j]     = (short)(q0[j] >> 16);
            a2h[4 + j] = (short)(q1[j] & 0xffff);
            a2l[4 + j] = (short)(q1[j] >> 16);
        }
        #pragma unroll
        for (int nt = 0; nt < 8; ++nt) {
            size_t o = (size_t)((ks * 8 + nt) * 64 + lane) * 8;
            short8 bh = *(const short8*)(Wu2H + o);
            short8 bl = *(const short8*)(Wu2L + o);
            u2[nt] = __builtin_amdgcn_mfma_f32_16x16x32_bf16(a2h, bh, u2[nt], 0, 0, 0);
            u2[nt] = __builtin_amdgcn_mfma_f32_16x16x32_bf16(a2l, bh, u2[nt], 0, 0, 0);
            u2[nt] = __builtin_amdgcn_mfma_f32_16x16x32_bf16(a2h, bl, u2[nt], 0, 0, 0);
        }
    }

    float s[4]  = {0.f, 0.f, 0.f, 0.f};
    float ss[4] = {0.f, 0.f, 0.f, 0.f};
    #pragma unroll
    for (int nt = 0; nt < 8; ++nt) {
        int col = nt * 16 + arow;
        float b2 = bu2[col];
        #pragma unroll
        for (int r = 0; r < 4; ++r) {
            int node = n0 + g4 * 4 + r;
            float xv = x[(size_t)node * 128 + col];
            float g  = ga[nt][r];
            float o  = g * (u2[nt][r] + b2) + (1.f - g) * xv;
            u2[nt][r] = o;
            s[r]  += o;
            ss[r] += o * o;
        }
    }
    #pragma unroll
    for (int off = 8; off >= 1; off >>= 1) {
        #pragma unroll
        for (int r = 0; r < 4; ++r) {
            s[r]  += __shfl_xor(s[r],  off);
            ss[r] += __shfl_xor(ss[r], off);
        }
    }
    float mu[4], rstd[4];
    #pragma unroll
    for (int r = 0; r < 4; ++r) {
        mu[r] = s[r] * (1.f / 128.f);
        float var = ss[r] * (1.f / 128.f) - mu[r] * mu[r];
        rstd[r] = rsqrtf(var + 1e-5f);
    }
    #pragma unroll
    for (int nt = 0; nt < 8; ++nt) {
        int col = nt * 16 + arow;
        float gm = gamma[col], bt = beta[col];
        #pragma unroll
        for (int r = 0; r < 4; ++r) {
            int node = n0 + g4 * 4 + r;
            if (node < N)
                out[(size_t)node * 128 + col] = (u2[nt][r] - mu[r]) * rstd[r] * gm + bt;
        }
    }
}

extern "C" void kernel_launch(void* const* d_in, const int* in_sizes, int n_in,
                              void* d_out, int out_size, void* d_ws, size_t ws_size,
                              hipStream_t stream)
{
    const float* x    = (const float*)d_in[0];
    const int*   ei   = (const int*)  d_in[1];
    const float* ea   = (const float*)d_in[2];
    const float* Wm1  = (const float*)d_in[3];
    const float* bm1  = (const float*)d_in[4];
    const float* Wm2  = (const float*)d_in[5];
    const float* bm2  = (const float*)d_in[6];
    const float* Wg   = (const float*)d_in[7];
    const float* bg   = (const float*)d_in[8];
    const float* Wu1  = (const float*)d_in[9];
    const float* bu1  = (const float*)d_in[10];
    const float* Wu2  = (const float*)d_in[11];
    const float* bu2  = (const float*)d_in[12];
    const float* gmma = (const float*)d_in[13];
    const float* beta = (const float*)d_in[14];
    float* out = (float*)d_out;

    const int N = in_sizes[0] / HID;
    const int E = in_sizes[1] / 2;

    // workspace carve-up (Tdst last so it degrades gracefully)
    float*          agg  = (float*)d_ws;                             // N*128 f32
    unsigned short* xb   = (unsigned short*)(agg + (size_t)N * HID); // N*128 bf16
    unsigned short* W1f  = xb + (size_t)N * HID;                     // 32768
    unsigned short* W2f  = W1f + 32768;                              // 16384
    unsigned short* WgH  = W2f + 16384;
    unsigned short* WgL  = WgH + 32768;
    unsigned short* Wu1H = WgL + 32768;
    unsigned short* Wu1L = Wu1H + 32768;
    unsigned short* Wu2H = Wu1L + 32768;
    unsigned short* Wu2L = Wu2H + 16384;
    unsigned* cnt  = (unsigned*)(Wu2L + 16384);   // N
    unsigned* cur  = cnt + N;                     // N
    int*      perm = (int*)(cur + N);             // E
    float*    Tdst = (float*)(perm + E);          // N*128 f32

    size_t need_perm = (size_t)((char*)(perm + E) - (char*)d_ws);
    size_t need_full = (size_t)((char*)(Tdst + (size_t)N * HID) - (char*)d_ws);
    const bool do_sort = (ws_size >= need_perm);
    const bool do_td   = (ws_size >= need_full);

    hipMemsetAsync(agg, 0, (size_t)N * HID * sizeof(float), stream);

    int n4 = N * HID / 4;
    prep_x<<<dim3((n4 + 255) / 256), dim3(256), 0, stream>>>((const float4*)x, xb, n4);
    prep_w<<<dim3(16), dim3(256), 0, stream>>>(Wm1, W1f, 8);
    prep_w<<<dim3(8),  dim3(256), 0, stream>>>(Wm2, W2f, 4);
    prep_w_split<<<dim3(16), dim3(256), 0, stream>>>(Wg,  WgH,  WgL,  8);
    prep_w_split<<<dim3(16), dim3(256), 0, stream>>>(Wu1, Wu1H, Wu1L, 8);
    prep_w_split<<<dim3(8),  dim3(256), 0, stream>>>(Wu2, Wu2H, Wu2L, 4);

    const int* permA = nullptr;
    if (do_sort) {
        hipMemsetAsync(cnt, 0, (size_t)N * sizeof(unsigned), stream);
        hist_k<<<dim3((E + 255) / 256), dim3(256), 0, stream>>>(ei, cnt, E);
        scan_k<<<dim3(1), dim3(1024), 0, stream>>>(cnt, cur, N);
        scatter_perm_k<<<dim3((E + 255) / 256), dim3(256), 0, stream>>>(ei, cur, perm, E);
        permA = perm;
    }

    dim3 egrid((E + 127) / 128);
    if (do_td) {
        dst_gemm<<<dim3((N + 63) / 64), dim3(256), 0, stream>>>(xb, W1f, Tdst, N);
        edge_mfma<true><<<egrid, dim3(256), 0, stream>>>(
            xb, ei, permA, ea, Tdst, W1f, W2f, Wm1 + 256 * HID, bm1, bm2, agg, E);
    } else {
        edge_mfma<false><<<egrid, dim3(256), 0, stream>>>(
            xb, ei, permA, ea, nullptr, W1f, W2f, Wm1 + 256 * HID, bm1, bm2, agg, E);
    }

    int ntiles = (N + 15) / 16;
    node_mfma<<<dim3((ntiles + 3) / 4), dim3(256), 0, stream>>>(
        x, agg, WgH, WgL, Wu1H, Wu1L, Wu2H, Wu2L,
        bg, bu1, bu2, gmma, beta, out, N);
}